// Round 1
// baseline (370.720 us; speedup 1.0000x reference)
//
#include <hip/hip_runtime.h>
#include <hip/hip_bf16.h>

typedef __attribute__((ext_vector_type(8))) short bf16x8;
typedef __attribute__((ext_vector_type(4))) float f32x4;
typedef unsigned short u16;

#define DEVI __device__ __forceinline__

DEVI u16 f2bf(float f){
  unsigned int u = __float_as_uint(f);
  u += 0x7FFF + ((u >> 16) & 1);
  return (u16)(u >> 16);
}

// ---------------- prep kernels ----------------

__global__ __launch_bounds__(256) void k_conv_hs(const float* __restrict__ src,
                                                 u16* __restrict__ dst, int n4){
  int idx = blockIdx.x * blockDim.x + threadIdx.x;
  int stride = gridDim.x * blockDim.x;
  for (int i = idx; i < n4; i += stride){
    float4 v = ((const float4*)src)[i];
    ushort4 o;
    o.x = f2bf(v.x); o.y = f2bf(v.y); o.z = f2bf(v.z); o.w = f2bf(v.w);
    ((ushort4*)dst)[i] = o;
  }
}

// W [k][n] f32  ->  Wt [n][k] bf16   (3 matrices)
__global__ __launch_bounds__(256) void k_trans_w(const float* __restrict__ w0,
    const float* __restrict__ w1, const float* __restrict__ w2, u16* __restrict__ Wt){
  __shared__ float t[32][33];
  int z = blockIdx.z;
  const float* W = z == 0 ? w0 : (z == 1 ? w1 : w2);
  u16* dst = Wt + z * 1048576;
  int tx = threadIdx.x, ty = threadIdx.y;
  int n = blockIdx.x * 32 + tx;
  for (int j = 0; j < 4; ++j){
    int k = blockIdx.y * 32 + ty + j * 8;
    t[ty + j * 8][tx] = W[k * 1024 + n];
  }
  __syncthreads();
  for (int j = 0; j < 4; ++j){
    int nrow = blockIdx.x * 32 + ty + j * 8;
    int kcol = blockIdx.y * 32 + tx;
    dst[nrow * 1024 + kcol] = f2bf(t[tx][ty + j * 8]);
  }
}

// rope table: cs[s*64+d] = {cos, sin} of s * 10000^(-(d%32)/32)
__global__ __launch_bounds__(256) void k_rope_cs(float2* __restrict__ cs){
  int idx = blockIdx.x * 256 + threadIdx.x;   // 2048*64 = 131072
  int d = idx & 63, s = idx >> 6;
  int i = d & 31;
  float invf = __expf(-(float)i / 32.f * 9.210340371976184f);
  float ang = (float)s * invf;
  cs[idx] = make_float2(cosf(ang), sinf(ang));
}

// ---------------- QKV projection GEMM ----------------
// C[m][n] = hs[m][:] @ W[:,n] + b[n];  epilogue: rope (q,k), 1/64 scale (q),
// write Qb/Kb as [bh][s][d] bf16, V transposed as Vt [bh][d][s] bf16.
__global__ __launch_bounds__(256) void k_qkv(const u16* __restrict__ hsb,
    const u16* __restrict__ Wt, const float* __restrict__ biasq,
    const float* __restrict__ biask, const float* __restrict__ biasv,
    const float2* __restrict__ cs,
    u16* __restrict__ Qb, u16* __restrict__ Kb, u16* __restrict__ Vt){
  __shared__ u16 At[128 * 64];
  __shared__ u16 Bt[128 * 64];
  int which = blockIdx.z;
  int n0 = blockIdx.x * 128, m0 = blockIdx.y * 128;
  const u16* Wb = Wt + which * 1048576;
  int tid = threadIdx.x, lane = tid & 63, wid = tid >> 6, g = lane >> 4, li = lane & 15;
  int wrow = (wid >> 1) * 64, wcol = (wid & 1) * 64;
  f32x4 zero = {0.f, 0.f, 0.f, 0.f};
  f32x4 acc[4][4];
  for (int i = 0; i < 4; ++i) for (int j = 0; j < 4; ++j) acc[i][j] = zero;

  for (int kt = 0; kt < 16; ++kt){
    __syncthreads();
    for (int p = 0; p < 4; ++p){
      int c = tid + p * 256;
      int row = c >> 3, ks = c & 7;
      *(uint4*)((char*)At + row * 128 + ((ks * 16) ^ ((row & 7) << 4))) =
          *(const uint4*)(hsb + (m0 + row) * 1024 + kt * 64 + ks * 8);
      *(uint4*)((char*)Bt + row * 128 + ((ks * 16) ^ ((row & 7) << 4))) =
          *(const uint4*)(Wb + (n0 + row) * 1024 + kt * 64 + ks * 8);
    }
    __syncthreads();
    for (int kk = 0; kk < 2; ++kk){
      bf16x8 af[4], bfr[4];
      for (int i = 0; i < 4; ++i){
        int row = wrow + i * 16 + li;
        af[i] = *(const bf16x8*)((char*)At + row * 128 + ((kk * 64 + g * 16) ^ ((row & 7) << 4)));
        int col = wcol + i * 16 + li;
        bfr[i] = *(const bf16x8*)((char*)Bt + col * 128 + ((kk * 64 + g * 16) ^ ((col & 7) << 4)));
      }
      for (int i = 0; i < 4; ++i)
        for (int j = 0; j < 4; ++j)
          acc[i][j] = __builtin_amdgcn_mfma_f32_16x16x32_bf16(af[i], bfr[j], acc[i][j], 0, 0, 0);
    }
  }

  // epilogue
  const float* bias = which == 0 ? biasq : (which == 1 ? biask : biasv);
  int b = m0 >> 11;                      // batch (block never straddles)
  int hbase = (n0 + wcol) >> 6;          // head
  float vals[4][4][4];
  for (int i = 0; i < 4; ++i)
    for (int j = 0; j < 4; ++j){
      float bb = bias[n0 + wcol + j * 16 + li];
      for (int r = 0; r < 4; ++r){
        float v = acc[i][j][r] + bb;
        if (which == 0) v *= 0.015625f;  // hd^-0.5 pre-scale * 1/sqrt(hd) folded
        vals[i][j][r] = v;
      }
    }
  if (which < 2){
    u16* dst = which == 0 ? Qb : Kb;
    for (int i = 0; i < 4; ++i)
      for (int j = 0; j < 4; ++j)
        for (int r = 0; r < 4; ++r){
          int m = m0 + wrow + i * 16 + g * 4 + r;
          int srow = m & 2047;
          int d = j * 16 + li;
          float2 c2 = cs[srow * 64 + d];
          float part = vals[i][j ^ 2][r];           // partner col d^32 (same lane)
          float o = vals[i][j][r] * c2.x + (d < 32 ? -part : part) * c2.y;
          dst[(((long)b * 16 + hbase) * 2048 + srow) * 64 + d] = f2bf(o);
        }
  } else {
    for (int i = 0; i < 4; ++i)
      for (int j = 0; j < 4; ++j){
        int sbase = (m0 + wrow + i * 16 + g * 4) & 2047;
        int d = j * 16 + li;
        ushort4 pk;
        pk.x = f2bf(vals[i][j][0]); pk.y = f2bf(vals[i][j][1]);
        pk.z = f2bf(vals[i][j][2]); pk.w = f2bf(vals[i][j][3]);
        *(ushort4*)(Vt + (((long)b * 16 + hbase) * 64 + d) * 2048 + sbase) = pk;
      }
  }
}

// ---------------- attention ----------------
// grid (16 q-tiles, 64 bh); 4 waves; wave w owns q rows [w*32, w*32+32).
// two-pass softmax: pass1 computes m,l per row; pass2 P=exp(s-m)/l, ctx^T = mfma(V^T, P^T).
__global__ __launch_bounds__(256) void k_attn(const u16* __restrict__ Qb,
    const u16* __restrict__ Kb, const u16* __restrict__ Vt, float* __restrict__ out){
  __shared__ u16 Kt[128 * 64];        // [kv][d], xor-swizzled rows
  __shared__ u16 Vl[64 * 128];        // [d][kv], xor-swizzled rows
  __shared__ u16 Pt[4][2][2048];      // per wave: [panel(q16)][q'][kv], swizzled
  int qt = blockIdx.x, bh = blockIdx.y;
  int tid = threadIdx.x, lane = tid & 63, w = tid >> 6, g = lane >> 4, li = lane & 15;

  bf16x8 qa[2][2];
  {
    const u16* Qp = Qb + ((long)bh * 2048 + qt * 128 + w * 32) * 64;
    for (int mi = 0; mi < 2; ++mi)
      for (int kk = 0; kk < 2; ++kk)
        qa[mi][kk] = *(const bf16x8*)(Qp + (mi * 16 + li) * 64 + kk * 32 + g * 8);
  }

  float mrow[2][4], lrow[2][4];
  for (int mi = 0; mi < 2; ++mi) for (int r = 0; r < 4; ++r){ mrow[mi][r] = -1e30f; lrow[mi][r] = 0.f; }

  // ---- pass 1: stats ----
  for (int t = 0; t < 16; ++t){
    __syncthreads();
    for (int p = 0; p < 4; ++p){
      int c = tid + p * 256;
      int kv = c >> 3, ks = c & 7;
      *(uint4*)((char*)Kt + kv * 128 + ((ks * 16) ^ ((kv & 7) << 4))) =
          *(const uint4*)(Kb + ((long)bh * 2048 + t * 128 + kv) * 64 + ks * 8);
    }
    __syncthreads();
    f32x4 sc[2][8];
    for (int ni = 0; ni < 8; ++ni){
      int kv = ni * 16 + li;
      bf16x8 kb0 = *(const bf16x8*)((char*)Kt + kv * 128 + ((g * 16) ^ ((kv & 7) << 4)));
      bf16x8 kb1 = *(const bf16x8*)((char*)Kt + kv * 128 + ((64 + g * 16) ^ ((kv & 7) << 4)));
      for (int mi = 0; mi < 2; ++mi){
        f32x4 a = {0.f, 0.f, 0.f, 0.f};
        a = __builtin_amdgcn_mfma_f32_16x16x32_bf16(qa[mi][0], kb0, a, 0, 0, 0);
        a = __builtin_amdgcn_mfma_f32_16x16x32_bf16(qa[mi][1], kb1, a, 0, 0, 0);
        sc[mi][ni] = a;
      }
    }
    for (int mi = 0; mi < 2; ++mi)
      for (int r = 0; r < 4; ++r){
        float tm = sc[mi][0][r];
        for (int ni = 1; ni < 8; ++ni) tm = fmaxf(tm, sc[mi][ni][r]);
        for (int st = 1; st < 16; st <<= 1) tm = fmaxf(tm, __shfl_xor(tm, st));
        float nm = fmaxf(mrow[mi][r], tm);
        float rs = 0.f;
        for (int ni = 0; ni < 8; ++ni) rs += __expf(sc[mi][ni][r] - nm);
        for (int st = 1; st < 16; st <<= 1) rs += __shfl_xor(rs, st);
        lrow[mi][r] = lrow[mi][r] * __expf(mrow[mi][r] - nm) + rs;
        mrow[mi][r] = nm;
      }
  }
  float rl[2][4];
  for (int mi = 0; mi < 2; ++mi) for (int r = 0; r < 4; ++r) rl[mi][r] = 1.f / lrow[mi][r];

  // ---- pass 2: P and PV ----
  f32x4 oc[4][2];
  {
    f32x4 zero = {0.f, 0.f, 0.f, 0.f};
    for (int i = 0; i < 4; ++i) for (int j = 0; j < 2; ++j) oc[i][j] = zero;
  }
  char* PtW = (char*)&Pt[w][0][0];
  for (int t = 0; t < 16; ++t){
    __syncthreads();
    for (int p = 0; p < 4; ++p){
      int c = tid + p * 256;
      int kv = c >> 3, ks = c & 7;
      *(uint4*)((char*)Kt + kv * 128 + ((ks * 16) ^ ((kv & 7) << 4))) =
          *(const uint4*)(Kb + ((long)bh * 2048 + t * 128 + kv) * 64 + ks * 8);
      int d = c >> 4, kvs = c & 15;
      *(uint4*)((char*)Vl + d * 256 + ((kvs * 16) ^ ((d & 7) << 4))) =
          *(const uint4*)(Vt + ((long)bh * 64 + d) * 2048 + t * 128 + kvs * 8);
    }
    __syncthreads();
    f32x4 sc[2][8];
    for (int ni = 0; ni < 8; ++ni){
      int kv = ni * 16 + li;
      bf16x8 kb0 = *(const bf16x8*)((char*)Kt + kv * 128 + ((g * 16) ^ ((kv & 7) << 4)));
      bf16x8 kb1 = *(const bf16x8*)((char*)Kt + kv * 128 + ((64 + g * 16) ^ ((kv & 7) << 4)));
      for (int mi = 0; mi < 2; ++mi){
        f32x4 a = {0.f, 0.f, 0.f, 0.f};
        a = __builtin_amdgcn_mfma_f32_16x16x32_bf16(qa[mi][0], kb0, a, 0, 0, 0);
        a = __builtin_amdgcn_mfma_f32_16x16x32_bf16(qa[mi][1], kb1, a, 0, 0, 0);
        sc[mi][ni] = a;
      }
    }
    for (int mi = 0; mi < 2; ++mi)
      for (int ni = 0; ni < 8; ++ni)
        for (int r = 0; r < 4; ++r){
          float pv = __expf(sc[mi][ni][r] - mrow[mi][r]) * rl[mi][r];
          int qp = g * 4 + r;
          int kv = ni * 16 + li;
          *(u16*)(PtW + mi * 4096 + qp * 256 + ((kv * 2) ^ ((qp & 7) << 4))) = f2bf(pv);
        }
    __syncthreads();
    for (int kk = 0; kk < 4; ++kk){
      bf16x8 pb0 = *(const bf16x8*)(PtW + 0 * 4096 + li * 256 + ((kk * 64 + g * 16) ^ ((li & 7) << 4)));
      bf16x8 pb1 = *(const bf16x8*)(PtW + 1 * 4096 + li * 256 + ((kk * 64 + g * 16) ^ ((li & 7) << 4)));
      for (int md = 0; md < 4; ++md){
        int d = md * 16 + li;
        bf16x8 va = *(const bf16x8*)((char*)Vl + d * 256 + ((kk * 64 + g * 16) ^ ((d & 7) << 4)));
        oc[md][0] = __builtin_amdgcn_mfma_f32_16x16x32_bf16(va, pb0, oc[md][0], 0, 0, 0);
        oc[md][1] = __builtin_amdgcn_mfma_f32_16x16x32_bf16(va, pb1, oc[md][1], 0, 0, 0);
      }
    }
  }

  // epilogue: ctx^T in C-layout (row=d, col=q') -> out[b][s][h*64+d]
  int b = bh >> 4, h = bh & 15;
  for (int md = 0; md < 4; ++md)
    for (int pan = 0; pan < 2; ++pan){
      int d0 = md * 16 + g * 4;
      int srow = qt * 128 + w * 32 + pan * 16 + li;
      float4 v;
      v.x = oc[md][pan][0]; v.y = oc[md][pan][1];
      v.z = oc[md][pan][2]; v.w = oc[md][pan][3];
      *(float4*)(out + (((long)b * 2048 + srow) * 1024) + h * 64 + d0) = v;
    }
}

// ---------------- launch ----------------
extern "C" void kernel_launch(void* const* d_in, const int* in_sizes, int n_in,
                              void* d_out, int out_size, void* d_ws, size_t ws_size,
                              hipStream_t stream){
  const float* hs  = (const float*)d_in[0];
  const float* Wq  = (const float*)d_in[1];
  const float* bq  = (const float*)d_in[2];
  const float* Wk  = (const float*)d_in[3];
  const float* bk  = (const float*)d_in[4];
  const float* Wv  = (const float*)d_in[5];
  const float* bvv = (const float*)d_in[6];
  float* out = (float*)d_out;
  char* ws = (char*)d_ws;

  u16*    hsb = (u16*)(ws);                 // 16 MB  bf16 hidden
  u16*    Wt  = (u16*)(ws + 16777216);      //  6 MB  bf16 W^T x3
  u16*    Qb  = (u16*)(ws + 23068672);      // 16 MB  Q  [bh][s][d]
  u16*    Kb  = (u16*)(ws + 39845888);      // 16 MB  K  [bh][s][d]
  u16*    Vt  = (u16*)(ws + 56623104);      // 16 MB  V^T[bh][d][s]
  float2* cs  = (float2*)(ws + 73400320);   //  1 MB  rope table

  k_conv_hs<<<dim3(2048), dim3(256), 0, stream>>>(hs, hsb, 2097152);
  k_trans_w<<<dim3(32, 32, 3), dim3(32, 8), 0, stream>>>(Wq, Wk, Wv, Wt);
  k_rope_cs<<<dim3(512), dim3(256), 0, stream>>>(cs);
  k_qkv<<<dim3(8, 64, 3), dim3(256), 0, stream>>>(hsb, Wt, bq, bk, bvv, cs, Qb, Kb, Vt);
  k_attn<<<dim3(16, 64), dim3(256), 0, stream>>>(Qb, Kb, Vt, out);
}